// Round 1
// baseline (751.241 us; speedup 1.0000x reference)
//
#include <hip/hip_runtime.h>

// AttentionSubsample (LeViT) fused MI355X implementation.
// Shapes: B=512, N=196 (14x14), NQ=49 (7x7), C=256, H=8, KD=16, VD=32.
// Strategy: f16 MFMA (fp32 accum) for all GEMMs; one block per (b,h) fuses
// kv-proj+norm, q-proj+norm, QK^T+bias, softmax, PV, hardswish; second GEMM
// kernel does the output projection + norm. BN params and the bias gather
// table are precomputed by a tiny prep kernel into workspace.

#define Bn   512
#define Nn   196
#define NQn  49
#define Cn   256
#define Hn   8
#define KDn  16
#define VDn  32
// per-head kv channels = KD+VD = 48

typedef float    float4v __attribute__((ext_vector_type(4)));
typedef _Float16 half8v  __attribute__((ext_vector_type(8)));
typedef _Float16 half4v  __attribute__((ext_vector_type(4)));

// ---------------------------------------------------------------- prep ----
__global__ __launch_bounds__(256) void prep_kernel(
    const float* __restrict__ g_kv, const float* __restrict__ b_kv,
    const float* __restrict__ m_kv, const float* __restrict__ v_kv,
    const float* __restrict__ g_q,  const float* __restrict__ b_q,
    const float* __restrict__ m_q,  const float* __restrict__ v_q,
    const float* __restrict__ g_p,  const float* __restrict__ b_p,
    const float* __restrict__ m_p,  const float* __restrict__ v_p,
    const float* __restrict__ ab,   const int* __restrict__ idxs,
    float* __restrict__ kv_s, float* __restrict__ kv_sh,
    float* __restrict__ q_s,  float* __restrict__ q_sh,
    float* __restrict__ p_s,  float* __restrict__ p_sh,
    float* __restrict__ bias_tab)
{
  int i = blockIdx.x * 256 + threadIdx.x;
  if (i < 384) {                       // kv norm:  y*s + (b - m*s)
    float s = g_kv[i] * rsqrtf(v_kv[i] + 1e-5f);
    kv_s[i] = s; kv_sh[i] = b_kv[i] - m_kv[i] * s;
  } else if (i < 512) {                // q norm, with 0.25 QK scale folded in
    int j = i - 384;
    float s = g_q[j] * rsqrtf(v_q[j] + 1e-5f);
    q_s[j] = 0.25f * s; q_sh[j] = 0.25f * (b_q[j] - m_q[j] * s);
  } else if (i < 896) {                // proj norm
    int j = i - 512;
    float s = g_p[j] * rsqrtf(v_p[j] + 1e-5f);
    p_s[j] = s; p_sh[j] = b_p[j] - m_p[j] * s;
  }
  int t = i - 896;                     // bias_tab[h][q][n] = ab[h, idxs[q,n]]
  if (t >= 0 && t < Hn * NQn * Nn) {
    int h = t / (NQn * Nn);
    int rem = t - h * (NQn * Nn);
    int q = rem / Nn, n = rem - q * Nn;
    bias_tab[t] = ab[h * Nn + idxs[q * Nn + n]];
  }
}

// ---------------------------------------------------------------- attn ----
// grid: 4096 = b*8 + h (h fastest => 8 XCDs share one x_b via LLC)
__global__ __launch_bounds__(256) void attn_kernel(
    const float* __restrict__ x,
    const float* __restrict__ Wkv, const float* __restrict__ Wq,
    const float* __restrict__ kv_s, const float* __restrict__ kv_sh,
    const float* __restrict__ q_s,  const float* __restrict__ q_sh,
    const float* __restrict__ bias_tab,
    _Float16* __restrict__ oh)
{
  const int bid = blockIdx.x;
  const int b = bid >> 3, h = bid & 7;
  const int tid = threadIdx.x, lane = tid & 63, wid = tid >> 6;
  const int row_in = lane & 15, kgrp = lane >> 4;

  // LDS: strides chosen for conflict-free MFMA fragment reads.
  __shared__ _Float16 sW[64][264];    // rows 0..47 kv-head W, 48..63 q-head W (33.8 KB)
  __shared__ _Float16 sk[208][20];    // k[n][d], pad rows zeroed              (8.3 KB)
  __shared__ _Float16 svT[32][212];   // v^T[vd][n], pad cols zeroed           (13.6 KB)
  __shared__ _Float16 sq[64][20];     // q[q][d], rows>=49 zeroed              (2.6 KB)
  __shared__ float    sS[49][208];    // logits                                (40.8 KB)
  __shared__ _Float16 sP[64][212];    // probs, rows>=49 zeroed                (27.1 KB)
  __shared__ float    sScale[64], sShift[64];

  // ---- phase 1: stage W head-slice (f32->f16), norm params, zero pads ----
  {
    int r = tid >> 2, c0 = (tid & 3) * 64;
    const float* src = (r < 48) ? (Wkv + (size_t)(h * 48 + r) * Cn)
                                : (Wq  + (size_t)(h * 16 + (r - 48)) * Cn);
#pragma unroll
    for (int c = c0; c < c0 + 64; c += 4) {
      float4v v = *reinterpret_cast<const float4v*>(src + c);
      half4v hv;
      hv[0] = (_Float16)v[0]; hv[1] = (_Float16)v[1];
      hv[2] = (_Float16)v[2]; hv[3] = (_Float16)v[3];
      *reinterpret_cast<half4v*>(&sW[r][c]) = hv;
    }
    if (tid < 48)      { sScale[tid] = kv_s[h * 48 + tid];      sShift[tid] = kv_sh[h * 48 + tid]; }
    else if (tid < 64) { sScale[tid] = q_s[h * 16 + (tid - 48)]; sShift[tid] = q_sh[h * 16 + (tid - 48)]; }
    if (tid < 240) sk[196 + tid / 20][tid % 20] = (_Float16)0.f;          // k pad rows
    for (int i = tid; i < 32 * 16; i += 256) svT[i >> 4][196 + (i & 15)] = (_Float16)0.f; // v pad cols
    for (int i = tid; i < 15 * 212; i += 256) sP[49 + i / 212][i % 212] = (_Float16)0.f;  // P pad rows
  }
  __syncthreads();

  // ---- phase 2: kv GEMM (196x48 = x_b(196x256) @ W^T) + q GEMM ----------
  // A-fragments straight from global memory (f32 -> f16 in-register).
  for (int mt = wid; mt < 13; mt += 4) {
    int n = mt * 16 + row_in;
    int nc = n < 195 ? n : 195;                   // clamp OOB rows (discarded)
    const float* xrow = x + ((size_t)(b * Nn + nc)) * Cn + kgrp * 8;
    float4v acc[3];
#pragma unroll
    for (int nt = 0; nt < 3; ++nt) acc[nt] = (float4v){0.f, 0.f, 0.f, 0.f};
#pragma unroll
    for (int kc = 0; kc < 8; ++kc) {
      float4v a0 = *reinterpret_cast<const float4v*>(xrow + kc * 32);
      float4v a1 = *reinterpret_cast<const float4v*>(xrow + kc * 32 + 4);
      half8v af;
      af[0] = (_Float16)a0[0]; af[1] = (_Float16)a0[1];
      af[2] = (_Float16)a0[2]; af[3] = (_Float16)a0[3];
      af[4] = (_Float16)a1[0]; af[5] = (_Float16)a1[1];
      af[6] = (_Float16)a1[2]; af[7] = (_Float16)a1[3];
#pragma unroll
      for (int nt = 0; nt < 3; ++nt) {
        half8v bf = *reinterpret_cast<const half8v*>(&sW[nt * 16 + row_in][kc * 32 + kgrp * 8]);
        acc[nt] = __builtin_amdgcn_mfma_f32_16x16x32_f16(af, bf, acc[nt], 0, 0, 0);
      }
    }
#pragma unroll
    for (int nt = 0; nt < 3; ++nt)
#pragma unroll
      for (int i = 0; i < 4; ++i) {
        int nrow = mt * 16 + kgrp * 4 + i;        // D row = output token n
        int j = nt * 16 + row_in;                 // D col = kv channel
        if (nrow < 196) {
          float y = acc[nt][i] * sScale[j] + sShift[j];
          if (j < 16) sk[nrow][j] = (_Float16)y;
          else        svT[j - 16][nrow] = (_Float16)y;
        }
      }
  }
  // q GEMM: 49 strided rows of x, one 16-col tile; wave w owns M-tile w
  {
    int qq = wid * 16 + row_in;
    int q2 = qq < 48 ? qq : 48;
    int qi = q2 / 7, qj = q2 - qi * 7;
    int nq = 28 * qi + 2 * qj;                    // source row in x
    const float* xrow = x + ((size_t)(b * Nn + nq)) * Cn + kgrp * 8;
    float4v acc = (float4v){0.f, 0.f, 0.f, 0.f};
#pragma unroll
    for (int kc = 0; kc < 8; ++kc) {
      float4v a0 = *reinterpret_cast<const float4v*>(xrow + kc * 32);
      float4v a1 = *reinterpret_cast<const float4v*>(xrow + kc * 32 + 4);
      half8v af;
      af[0] = (_Float16)a0[0]; af[1] = (_Float16)a0[1];
      af[2] = (_Float16)a0[2]; af[3] = (_Float16)a0[3];
      af[4] = (_Float16)a1[0]; af[5] = (_Float16)a1[1];
      af[6] = (_Float16)a1[2]; af[7] = (_Float16)a1[3];
      half8v bf = *reinterpret_cast<const half8v*>(&sW[48 + row_in][kc * 32 + kgrp * 8]);
      acc = __builtin_amdgcn_mfma_f32_16x16x32_f16(af, bf, acc, 0, 0, 0);
    }
#pragma unroll
    for (int i = 0; i < 4; ++i) {
      int qrow = wid * 16 + kgrp * 4 + i;
      int d = row_in;
      float y = (qrow < 49) ? (acc[i] * sScale[48 + d] + sShift[48 + d]) : 0.f;
      sq[qrow][d] = (_Float16)y;                  // rows>=49 get zeros
    }
  }
  __syncthreads();

  // ---- phase 3: S = q @ k^T (scale pre-folded) + bias -------------------
  {
    half4v aq[4];
#pragma unroll
    for (int mt = 0; mt < 4; ++mt)
      aq[mt] = *reinterpret_cast<const half4v*>(&sq[mt * 16 + row_in][kgrp * 4]);
    for (int nt = wid; nt < 13; nt += 4) {
      half4v bk = *reinterpret_cast<const half4v*>(&sk[nt * 16 + row_in][kgrp * 4]);
      float4v accs[4];
#pragma unroll
      for (int mt = 0; mt < 4; ++mt) accs[mt] = (float4v){0.f, 0.f, 0.f, 0.f};
#pragma unroll
      for (int mt = 0; mt < 4; ++mt)
        accs[mt] = __builtin_amdgcn_mfma_f32_16x16x16f16(aq[mt], bk, accs[mt], 0, 0, 0);
#pragma unroll
      for (int mt = 0; mt < 4; ++mt)
#pragma unroll
        for (int i = 0; i < 4; ++i) {
          int q = mt * 16 + kgrp * 4 + i;
          int n = nt * 16 + row_in;
          if (q < 49 && n < 196)
            sS[q][n] = accs[mt][i] + bias_tab[((size_t)(h * NQn + q)) * Nn + n];
        }
    }
  }
  __syncthreads();

  // ---- phase 4: wave-parallel softmax rows ------------------------------
  for (int r = wid; r < 49; r += 4) {
    float v[4];
#pragma unroll
    for (int t = 0; t < 4; ++t) {
      int c = lane + t * 64;
      v[t] = (c < 196) ? sS[r][c] : -1e30f;
    }
    float m = fmaxf(fmaxf(v[0], v[1]), fmaxf(v[2], v[3]));
#pragma unroll
    for (int off = 32; off >= 1; off >>= 1) m = fmaxf(m, __shfl_xor(m, off, 64));
    float e[4], s = 0.f;
#pragma unroll
    for (int t = 0; t < 4; ++t) { e[t] = __expf(v[t] - m); s += e[t]; }
#pragma unroll
    for (int off = 32; off >= 1; off >>= 1) s += __shfl_xor(s, off, 64);
    float inv = 1.f / s;
#pragma unroll
    for (int t = 0; t < 4; ++t) {
      int c = lane + t * 64;
      if (c < 212) sP[r][c] = (_Float16)((c < 196) ? e[t] * inv : 0.f);
    }
  }
  __syncthreads();

  // ---- phase 5: O = P @ V, hardswish, store f16 -------------------------
  {
    int mt = wid;                                 // 4 waves, 4 q-tiles
    float4v acc[2];
    acc[0] = (float4v){0.f, 0.f, 0.f, 0.f};
    acc[1] = (float4v){0.f, 0.f, 0.f, 0.f};
#pragma unroll
    for (int kc = 0; kc < 13; ++kc) {
      half4v ap = *reinterpret_cast<const half4v*>(&sP[mt * 16 + row_in][kc * 16 + kgrp * 4]);
#pragma unroll
      for (int nt = 0; nt < 2; ++nt) {
        half4v bv = *reinterpret_cast<const half4v*>(&svT[nt * 16 + row_in][kc * 16 + kgrp * 4]);
        acc[nt] = __builtin_amdgcn_mfma_f32_16x16x16f16(ap, bv, acc[nt], 0, 0, 0);
      }
    }
#pragma unroll
    for (int nt = 0; nt < 2; ++nt)
#pragma unroll
      for (int i = 0; i < 4; ++i) {
        int q = mt * 16 + kgrp * 4 + i;
        if (q < 49) {
          float o = acc[nt][i];
          float t6 = fminf(fmaxf(o + 3.f, 0.f), 6.f);
          float hs = o * t6 * (1.f / 6.f);
          oh[((size_t)(b * NQn + q)) * 256 + h * 32 + nt * 16 + row_in] = (_Float16)hs;
        }
      }
  }
}

// ---------------------------------------------------------------- proj ----
// out[r][j] = hs_o[r][:] @ Wp[j][:] * s[j] + sh[j];  M=25088, K=256, N=384
__global__ __launch_bounds__(256) void proj_kernel(
    const _Float16* __restrict__ oh, const float* __restrict__ Wp,
    const float* __restrict__ p_s, const float* __restrict__ p_sh,
    float* __restrict__ out)
{
  const int mblk = blockIdx.x;                    // 0..391
  const int nblk = blockIdx.y;                    // 0..5
  const int tid = threadIdx.x, lane = tid & 63, wid = tid >> 6;
  const int row_in = lane & 15, kgrp = lane >> 4;

  __shared__ _Float16 sW[64][264];
  __shared__ float sScale[64], sShift[64];
  {
    int r = tid >> 2, c0 = (tid & 3) * 64;
    const float* src = Wp + (size_t)(nblk * 64 + r) * Cn;
#pragma unroll
    for (int c = c0; c < c0 + 64; c += 4) {
      float4v v = *reinterpret_cast<const float4v*>(src + c);
      half4v hv;
      hv[0] = (_Float16)v[0]; hv[1] = (_Float16)v[1];
      hv[2] = (_Float16)v[2]; hv[3] = (_Float16)v[3];
      *reinterpret_cast<half4v*>(&sW[r][c]) = hv;
    }
    if (tid < 64) { sScale[tid] = p_s[nblk * 64 + tid]; sShift[tid] = p_sh[nblk * 64 + tid]; }
  }
  __syncthreads();

  const int m0 = mblk * 64 + wid * 16;
  const _Float16* arow = oh + (size_t)(m0 + row_in) * 256 + kgrp * 8;
  float4v acc[4];
#pragma unroll
  for (int nt = 0; nt < 4; ++nt) acc[nt] = (float4v){0.f, 0.f, 0.f, 0.f};
#pragma unroll
  for (int kc = 0; kc < 8; ++kc) {
    half8v af = *reinterpret_cast<const half8v*>(arow + kc * 32);
#pragma unroll
    for (int nt = 0; nt < 4; ++nt) {
      half8v bf = *reinterpret_cast<const half8v*>(&sW[nt * 16 + row_in][kc * 32 + kgrp * 8]);
      acc[nt] = __builtin_amdgcn_mfma_f32_16x16x32_f16(af, bf, acc[nt], 0, 0, 0);
    }
  }
#pragma unroll
  for (int nt = 0; nt < 4; ++nt)
#pragma unroll
    for (int i = 0; i < 4; ++i) {
      int r = m0 + kgrp * 4 + i;
      int j = nt * 16 + row_in;
      float y = acc[nt][i] * sScale[j] + sShift[j];
      out[(size_t)r * 384 + nblk * 64 + j] = y;
    }
}

// -------------------------------------------------------------- launch ----
extern "C" void kernel_launch(void* const* d_in, const int* in_sizes, int n_in,
                              void* d_out, int out_size, void* d_ws, size_t ws_size,
                              hipStream_t stream) {
  const float* x    = (const float*)d_in[0];
  const float* Wkv  = (const float*)d_in[1];
  const float* g_kv = (const float*)d_in[2];
  const float* b_kv = (const float*)d_in[3];
  const float* m_kv = (const float*)d_in[4];
  const float* v_kv = (const float*)d_in[5];
  const float* Wq   = (const float*)d_in[6];
  const float* g_q  = (const float*)d_in[7];
  const float* b_q  = (const float*)d_in[8];
  const float* m_q  = (const float*)d_in[9];
  const float* v_q  = (const float*)d_in[10];
  const float* Wp   = (const float*)d_in[11];
  const float* g_p  = (const float*)d_in[12];
  const float* b_p  = (const float*)d_in[13];
  const float* m_p  = (const float*)d_in[14];
  const float* v_p  = (const float*)d_in[15];
  const float* ab   = (const float*)d_in[16];
  const int*   idxs = (const int*)d_in[17];
  float* out = (float*)d_out;

  // workspace carve (≈12.6 MB total)
  char* w = (char*)d_ws;
  _Float16* oh       = (_Float16*)w;                    // 25088*256*2 = 12,845,056
  float*    bias_tab = (float*)(w + 12845056);          // 8*49*196*4 =    307,328
  float*    kv_s     = (float*)(w + 13152384);          // 1536
  float*    kv_sh    = (float*)(w + 13153920);          // 1536
  float*    q_s      = (float*)(w + 13155456);          // 512
  float*    q_sh     = (float*)(w + 13155968);          // 512
  float*    p_s      = (float*)(w + 13156480);          // 1536
  float*    p_sh     = (float*)(w + 13158016);          // 1536

  prep_kernel<<<304, 256, 0, stream>>>(g_kv, b_kv, m_kv, v_kv,
                                       g_q, b_q, m_q, v_q,
                                       g_p, b_p, m_p, v_p,
                                       ab, idxs,
                                       kv_s, kv_sh, q_s, q_sh, p_s, p_sh, bias_tab);
  attn_kernel<<<Bn * Hn, 256, 0, stream>>>(x, Wkv, Wq, kv_s, kv_sh, q_s, q_sh,
                                           bias_tab, oh);
  proj_kernel<<<dim3(392, 6), 256, 0, stream>>>(oh, Wp, p_s, p_sh, out);
}

// Round 2
// 478.680 us; speedup vs baseline: 1.5694x; 1.5694x over previous
//
#include <hip/hip_runtime.h>

// AttentionSubsample (LeViT) — split-stage MI355X implementation, round 2.
// B=512, N=196, NQ=49, C=256, H=8, KD=16, VD=32.
// prep: f32->f16 weight conversion, BN scale/shift folding, bias gather (transposed).
// kv_gemm: k,v^T f16 workspaces.  q_gemm: q f16 workspace (0.25 scale folded).
// attn: per (b,h), register softmax, P via tiny per-wave LDS, no barriers.
// proj: 64-row x 384-col blocks, weights from L2.

#define Bn   512
#define Nn   196
#define NQn  49
#define Cn   256
#define Hn   8

typedef float    float4v __attribute__((ext_vector_type(4)));
typedef _Float16 half8v  __attribute__((ext_vector_type(8)));
typedef _Float16 half4v  __attribute__((ext_vector_type(4)));

// ---------------------------------------------------------------- prep ----
__global__ __launch_bounds__(256) void prep_kernel(
    const float* __restrict__ Wkv, const float* __restrict__ Wq,
    const float* __restrict__ Wp,
    const float* __restrict__ g_kv, const float* __restrict__ b_kv,
    const float* __restrict__ m_kv, const float* __restrict__ v_kv,
    const float* __restrict__ g_q,  const float* __restrict__ b_q,
    const float* __restrict__ m_q,  const float* __restrict__ v_q,
    const float* __restrict__ g_p,  const float* __restrict__ b_p,
    const float* __restrict__ m_p,  const float* __restrict__ v_p,
    const float* __restrict__ ab,   const int* __restrict__ idxs,
    _Float16* __restrict__ Whkv, _Float16* __restrict__ Whq,
    _Float16* __restrict__ Whp,
    float* __restrict__ kv_s, float* __restrict__ kv_sh,
    float* __restrict__ q_s,  float* __restrict__ q_sh,
    float* __restrict__ p_s,  float* __restrict__ p_sh,
    float* __restrict__ biasT)
{
  int i = blockIdx.x * 256 + threadIdx.x;
  if (i < 98304) { Whkv[i] = (_Float16)Wkv[i]; return; }
  i -= 98304;
  if (i < 32768) { Whq[i] = (_Float16)Wq[i]; return; }
  i -= 32768;
  if (i < 98304) { Whp[i] = (_Float16)Wp[i]; return; }
  i -= 98304;
  if (i < 896) {
    if (i < 384) {
      float s = g_kv[i] * rsqrtf(v_kv[i] + 1e-5f);
      kv_s[i] = s; kv_sh[i] = b_kv[i] - m_kv[i] * s;
    } else if (i < 512) {
      int j = i - 384;
      float s = g_q[j] * rsqrtf(v_q[j] + 1e-5f);
      q_s[j] = 0.25f * s; q_sh[j] = 0.25f * (b_q[j] - m_q[j] * s);
    } else {
      int j = i - 512;
      float s = g_p[j] * rsqrtf(v_p[j] + 1e-5f);
      p_s[j] = s; p_sh[j] = b_p[j] - m_p[j] * s;
    }
    return;
  }
  i -= 896;
  if (i < Hn * NQn * Nn) {                       // biasT[h][n][64] = ab[h, idxs[q,n]]
    unsigned h = (unsigned)i / (NQn * Nn);
    unsigned rem = (unsigned)i - h * (NQn * Nn);
    unsigned q = rem / Nn, n = rem - q * Nn;
    biasT[((size_t)h * 208 + n) * 64 + q] = ab[h * Nn + idxs[q * Nn + n]];
  }
}

// ------------------------------------------------------------- kv gemm ----
// grid 1568: 64 rows x all 384 cols.  A from global f32 (held in regs),
// B-frags directly from f16 weights in L2.  Writes k[bh][208][16] (pad rows
// garbage-ok) and vT[bh][32][208] (pad cols garbage-ok, killed by P=0).
__global__ __launch_bounds__(256, 6) void kv_gemm_kernel(
    const float* __restrict__ x, const _Float16* __restrict__ Whkv,
    const float* __restrict__ kv_s, const float* __restrict__ kv_sh,
    _Float16* __restrict__ kk, _Float16* __restrict__ vT)
{
  const int tid = threadIdx.x, lane = tid & 63, wid = tid >> 6;
  const int row_in = lane & 15, kgrp = lane >> 4;
  const size_t g_a = (size_t)blockIdx.x * 64 + wid * 16 + row_in;

  half8v af[8];
  const float* xrow = x + g_a * Cn + kgrp * 8;
#pragma unroll
  for (int kc = 0; kc < 8; ++kc) {
    float4v a0 = *reinterpret_cast<const float4v*>(xrow + kc * 32);
    float4v a1 = *reinterpret_cast<const float4v*>(xrow + kc * 32 + 4);
    half8v t;
    t[0]=(_Float16)a0[0]; t[1]=(_Float16)a0[1]; t[2]=(_Float16)a0[2]; t[3]=(_Float16)a0[3];
    t[4]=(_Float16)a1[0]; t[5]=(_Float16)a1[1]; t[6]=(_Float16)a1[2]; t[7]=(_Float16)a1[3];
    af[kc] = t;
  }
  int b_[4], n_[4];
#pragma unroll
  for (int i = 0; i < 4; ++i) {
    unsigned g = blockIdx.x * 64 + wid * 16 + kgrp * 4 + i;
    unsigned b = g / 196u;
    b_[i] = b; n_[i] = g - b * 196u;
  }
#pragma unroll
  for (int nt = 0; nt < 24; ++nt) {
    float4v acc = (float4v){0.f, 0.f, 0.f, 0.f};
    const _Float16* wrow = Whkv + (size_t)(nt * 16 + row_in) * Cn + kgrp * 8;
#pragma unroll
    for (int kc = 0; kc < 8; ++kc) {
      half8v bf = *reinterpret_cast<const half8v*>(wrow + kc * 32);
      acc = __builtin_amdgcn_mfma_f32_16x16x32_f16(af[kc], bf, acc, 0, 0, 0);
    }
    int j = nt * 16 + row_in;
    float s = kv_s[j], sh = kv_sh[j];
    unsigned h = (unsigned)j / 48u, c = (unsigned)j - h * 48u;
#pragma unroll
    for (int i = 0; i < 4; ++i) {
      float y = acc[i] * s + sh;
      size_t bh = (size_t)b_[i] * 8 + h;
      if (c < 16) kk[(bh * 208 + n_[i]) * 16 + c] = (_Float16)y;
      else        vT[(bh * 32 + (c - 16)) * 208 + n_[i]] = (_Float16)y;
    }
  }
}

// -------------------------------------------------------------- q gemm ----
// grid 392: 64 q-rows x 128 cols. Writes qh[bh][64][16], rows>=49 garbage-ok.
__global__ __launch_bounds__(256, 6) void q_gemm_kernel(
    const float* __restrict__ x, const _Float16* __restrict__ Whq,
    const float* __restrict__ q_s, const float* __restrict__ q_sh,
    _Float16* __restrict__ qh)
{
  const int tid = threadIdx.x, lane = tid & 63, wid = tid >> 6;
  const int row_in = lane & 15, kgrp = lane >> 4;

  unsigned g = blockIdx.x * 64 + wid * 16 + row_in;      // 0..25087
  unsigned b = g / 49u, qq = g - b * 49u;
  unsigned qi = qq / 7u, qj = qq - qi * 7u;
  unsigned n = 28u * qi + 2u * qj;
  const float* xrow = x + ((size_t)b * Nn + n) * Cn + kgrp * 8;

  half8v af[8];
#pragma unroll
  for (int kc = 0; kc < 8; ++kc) {
    float4v a0 = *reinterpret_cast<const float4v*>(xrow + kc * 32);
    float4v a1 = *reinterpret_cast<const float4v*>(xrow + kc * 32 + 4);
    half8v t;
    t[0]=(_Float16)a0[0]; t[1]=(_Float16)a0[1]; t[2]=(_Float16)a0[2]; t[3]=(_Float16)a0[3];
    t[4]=(_Float16)a1[0]; t[5]=(_Float16)a1[1]; t[6]=(_Float16)a1[2]; t[7]=(_Float16)a1[3];
    af[kc] = t;
  }
  unsigned b2_[4], q2_[4];
#pragma unroll
  for (int i = 0; i < 4; ++i) {
    unsigned gg = blockIdx.x * 64 + wid * 16 + kgrp * 4 + i;
    unsigned bb = gg / 49u;
    b2_[i] = bb; q2_[i] = gg - bb * 49u;
  }
#pragma unroll
  for (int nt = 0; nt < 8; ++nt) {
    float4v acc = (float4v){0.f, 0.f, 0.f, 0.f};
    const _Float16* wrow = Whq + (size_t)(nt * 16 + row_in) * Cn + kgrp * 8;
#pragma unroll
    for (int kc = 0; kc < 8; ++kc) {
      half8v bf = *reinterpret_cast<const half8v*>(wrow + kc * 32);
      acc = __builtin_amdgcn_mfma_f32_16x16x32_f16(af[kc], bf, acc, 0, 0, 0);
    }
    int j = nt * 16 + row_in;                    // 0..127
    float s = q_s[j], sh = q_sh[j];
    int h = j >> 4, c = j & 15;
#pragma unroll
    for (int i = 0; i < 4; ++i) {
      float y = acc[i] * s + sh;
      qh[(((size_t)b2_[i] * 8 + h) * 64 + q2_[i]) * 16 + c] = (_Float16)y;
    }
  }
}

// ---------------------------------------------------------------- attn ----
// grid 4096 (b*8+h). 4 waves, wave w owns q-tile rows w*16..w*16+15.
// Register softmax (each q-row lives in one 16-lane group); only LDS is the
// per-wave P buffer for the layout change into PV's A-operand. No barriers.
__global__ __launch_bounds__(256, 4) void attn_kernel(
    const _Float16* __restrict__ kk, const _Float16* __restrict__ vT,
    const _Float16* __restrict__ qh, const float* __restrict__ biasT,
    _Float16* __restrict__ oh)
{
  const int bh = blockIdx.x;
  const int b = bh >> 3, h = bh & 7;
  const int tid = threadIdx.x, lane = tid & 63, wid = tid >> 6;
  const int row_in = lane & 15, kgrp = lane >> 4;

  __shared__ _Float16 sP[4][16][212];

  // ---- QK^T + bias, logits in registers -------------------------------
  half4v aq = *reinterpret_cast<const half4v*>(
      qh + ((size_t)bh * 64 + wid * 16 + row_in) * 16 + kgrp * 4);
  const _Float16* kbase = kk + (size_t)bh * 208 * 16;
  const float* bbase = biasT + ((size_t)h * 208) * 64 + wid * 16 + kgrp * 4;

  float4v acc[13];
#pragma unroll
  for (int nt = 0; nt < 13; ++nt) {
    half4v bk = *reinterpret_cast<const half4v*>(kbase + (nt * 16 + row_in) * 16 + kgrp * 4);
    float4v a = (float4v){0.f, 0.f, 0.f, 0.f};
    a = __builtin_amdgcn_mfma_f32_16x16x16f16(aq, bk, a, 0, 0, 0);
    float4v bias = *reinterpret_cast<const float4v*>(bbase + (size_t)(nt * 16 + row_in) * 64);
    acc[nt] = a + bias;
  }

  // ---- register softmax: row q lives in 16-lane group (kgrp*4+i) -------
  const bool tail_ok = (row_in < 4);             // nt=12 -> n=192+row_in valid iff <196
  float mx[4], sm[4];
#pragma unroll
  for (int i = 0; i < 4; ++i) mx[i] = -1e30f;
#pragma unroll
  for (int nt = 0; nt < 13; ++nt) {
    bool valid = (nt < 12) | tail_ok;
#pragma unroll
    for (int i = 0; i < 4; ++i)
      mx[i] = fmaxf(mx[i], valid ? acc[nt][i] : -1e30f);
  }
#pragma unroll
  for (int i = 0; i < 4; ++i) {
#pragma unroll
    for (int off = 8; off >= 1; off >>= 1)
      mx[i] = fmaxf(mx[i], __shfl_xor(mx[i], off, 64));
  }
#pragma unroll
  for (int i = 0; i < 4; ++i) sm[i] = 0.f;
#pragma unroll
  for (int nt = 0; nt < 13; ++nt) {
    bool valid = (nt < 12) | tail_ok;
#pragma unroll
    for (int i = 0; i < 4; ++i) {
      float e = valid ? __expf(acc[nt][i] - mx[i]) : 0.f;
      acc[nt][i] = e; sm[i] += e;
    }
  }
#pragma unroll
  for (int i = 0; i < 4; ++i) {
#pragma unroll
    for (int off = 8; off >= 1; off >>= 1)
      sm[i] += __shfl_xor(sm[i], off, 64);
  }
  float inv[4];
#pragma unroll
  for (int i = 0; i < 4; ++i) inv[i] = 1.f / sm[i];

  // ---- P -> per-wave LDS (layout change for PV A-operand) --------------
#pragma unroll
  for (int nt = 0; nt < 13; ++nt)
#pragma unroll
    for (int i = 0; i < 4; ++i)
      sP[wid][kgrp * 4 + i][nt * 16 + row_in] = (_Float16)(acc[nt][i] * inv[i]);

  // ---- O = P @ V (vT frags straight from global), hardswish, store -----
  const _Float16* vbase = vT + (size_t)bh * 32 * 208 + kgrp * 4;
  float4v o0 = (float4v){0.f, 0.f, 0.f, 0.f};
  float4v o1 = (float4v){0.f, 0.f, 0.f, 0.f};
#pragma unroll
  for (int kc = 0; kc < 13; ++kc) {
    half4v ap = *reinterpret_cast<const half4v*>(&sP[wid][row_in][kc * 16 + kgrp * 4]);
    half4v bv0 = *reinterpret_cast<const half4v*>(vbase + (size_t)row_in * 208 + kc * 16);
    half4v bv1 = *reinterpret_cast<const half4v*>(vbase + (size_t)(16 + row_in) * 208 + kc * 16);
    o0 = __builtin_amdgcn_mfma_f32_16x16x16f16(ap, bv0, o0, 0, 0, 0);
    o1 = __builtin_amdgcn_mfma_f32_16x16x16f16(ap, bv1, o1, 0, 0, 0);
  }
#pragma unroll
  for (int i = 0; i < 4; ++i) {
    int q = wid * 16 + kgrp * 4 + i;
    if (q < NQn) {
      size_t base = ((size_t)b * NQn + q) * 256 + h * 32 + row_in;
      float v0 = o0[i], v1 = o1[i];
      float hs0 = v0 * fminf(fmaxf(v0 + 3.f, 0.f), 6.f) * (1.f / 6.f);
      float hs1 = v1 * fminf(fmaxf(v1 + 3.f, 0.f), 6.f) * (1.f / 6.f);
      oh[base]      = (_Float16)hs0;
      oh[base + 16] = (_Float16)hs1;
    }
  }
}

// ---------------------------------------------------------------- proj ----
// grid 392: 64 rows x all 384 cols; A (f16) in regs, W f16 from L2.
__global__ __launch_bounds__(256, 6) void proj_kernel(
    const _Float16* __restrict__ oh, const _Float16* __restrict__ Whp,
    const float* __restrict__ p_s, const float* __restrict__ p_sh,
    float* __restrict__ out)
{
  const int tid = threadIdx.x, lane = tid & 63, wid = tid >> 6;
  const int row_in = lane & 15, kgrp = lane >> 4;
  const size_t g_a = (size_t)blockIdx.x * 64 + wid * 16 + row_in;

  half8v af[8];
  const _Float16* arow = oh + g_a * 256 + kgrp * 8;
#pragma unroll
  for (int kc = 0; kc < 8; ++kc)
    af[kc] = *reinterpret_cast<const half8v*>(arow + kc * 32);

  const size_t r0 = (size_t)blockIdx.x * 64 + wid * 16 + kgrp * 4;
#pragma unroll
  for (int nt = 0; nt < 24; ++nt) {
    float4v acc = (float4v){0.f, 0.f, 0.f, 0.f};
    const _Float16* wrow = Whp + (size_t)(nt * 16 + row_in) * Cn + kgrp * 8;
#pragma unroll
    for (int kc = 0; kc < 8; ++kc) {
      half8v bf = *reinterpret_cast<const half8v*>(wrow + kc * 32);
      acc = __builtin_amdgcn_mfma_f32_16x16x32_f16(af[kc], bf, acc, 0, 0, 0);
    }
    int j = nt * 16 + row_in;
    float s = p_s[j], sh = p_sh[j];
#pragma unroll
    for (int i = 0; i < 4; ++i)
      out[(r0 + i) * 384 + j] = acc[i] * s + sh;
  }
}

// -------------------------------------------------------------- launch ----
extern "C" void kernel_launch(void* const* d_in, const int* in_sizes, int n_in,
                              void* d_out, int out_size, void* d_ws, size_t ws_size,
                              hipStream_t stream) {
  const float* x    = (const float*)d_in[0];
  const float* Wkv  = (const float*)d_in[1];
  const float* g_kv = (const float*)d_in[2];
  const float* b_kv = (const float*)d_in[3];
  const float* m_kv = (const float*)d_in[4];
  const float* v_kv = (const float*)d_in[5];
  const float* Wq   = (const float*)d_in[6];
  const float* g_q  = (const float*)d_in[7];
  const float* b_q  = (const float*)d_in[8];
  const float* m_q  = (const float*)d_in[9];
  const float* v_q  = (const float*)d_in[10];
  const float* Wp   = (const float*)d_in[11];
  const float* g_p  = (const float*)d_in[12];
  const float* b_p  = (const float*)d_in[13];
  const float* m_p  = (const float*)d_in[14];
  const float* v_p  = (const float*)d_in[15];
  const float* ab   = (const float*)d_in[16];
  const int*   idxs = (const int*)d_in[17];
  float* out = (float*)d_out;

  // workspace carve (~104 MB)
  char* w = (char*)d_ws;
  _Float16* oh    = (_Float16*)(w);                     // 25088*256*2   = 12,845,056
  _Float16* kk    = (_Float16*)(w + 12845056);          // 4096*208*16*2 = 27,262,976
  _Float16* vT    = (_Float16*)(w + 40108032);          // 4096*32*208*2 = 54,525,952
  _Float16* qh    = (_Float16*)(w + 94633984);          // 4096*64*16*2  =  8,388,608
  _Float16* Whkv  = (_Float16*)(w + 103022592);         // 384*256*2     =    196,608
  _Float16* Whq   = (_Float16*)(w + 103219200);         // 128*256*2     =     65,536
  _Float16* Whp   = (_Float16*)(w + 103284736);         // 384*256*2     =    196,608
  float*    biasT = (float*)   (w + 103481344);         // 8*208*64*4    =    425,984
  float*    kv_s  = (float*)   (w + 103907328);
  float*    kv_sh = (float*)   (w + 103908864);
  float*    q_s   = (float*)   (w + 103910400);
  float*    q_sh  = (float*)   (w + 103910912);
  float*    p_s   = (float*)   (w + 103911424);
  float*    p_sh  = (float*)   (w + 103912960);

  prep_kernel<<<1200, 256, 0, stream>>>(Wkv, Wq, Wp,
                                        g_kv, b_kv, m_kv, v_kv,
                                        g_q, b_q, m_q, v_q,
                                        g_p, b_p, m_p, v_p,
                                        ab, idxs,
                                        Whkv, Whq, Whp,
                                        kv_s, kv_sh, q_s, q_sh, p_s, p_sh, biasT);
  kv_gemm_kernel<<<1568, 256, 0, stream>>>(x, Whkv, kv_s, kv_sh, kk, vT);
  q_gemm_kernel<<<392, 256, 0, stream>>>(x, Whq, q_s, q_sh, qh);
  attn_kernel<<<Bn * Hn, 256, 0, stream>>>(kk, vT, qh, biasT, oh);
  proj_kernel<<<392, 256, 0, stream>>>(oh, Whp, p_s, p_sh, out);
}